// Round 15
// baseline (225.691 us; speedup 1.0000x reference)
//
#include <hip/hip_runtime.h>
#include <math.h>

#define EPS 1e-5f

constexpr int Bb  = 128;
constexpr int C   = 256;
constexpr int Nz  = 169;   // 13*13
constexpr int Nx  = 625;   // 25*25
constexpr int NzP = 192;   // Nz padded (zero-filled)

typedef __bf16 bf16x8 __attribute__((ext_vector_type(8)));
typedef float  f32x4  __attribute__((ext_vector_type(4)));

__device__ __forceinline__ unsigned short f2bf(float f) {
    union { float f; unsigned u; } x; x.f = f;
    unsigned r = x.u + 0x7FFFu + ((x.u >> 16) & 1u);   // RNE
    return (unsigned short)(r >> 16);
}
__device__ __forceinline__ float bf2f(unsigned short h) {
    union { unsigned u; float f; } x; x.u = ((unsigned)h) << 16;
    return x.f;
}

// ---------------------------------------------------------------------------
// prep_all: all mutually-independent precomputes in ONE launch (unchanged).
// ---------------------------------------------------------------------------
__global__ __launch_bounds__(256)
void prep_all(const float* __restrict__ zf,
              const float* __restrict__ Wq, const float* __restrict__ bq,
              const float* __restrict__ Ws, const float* __restrict__ bs,
              const float* __restrict__ Wg, const float* __restrict__ Wf,
              unsigned short* __restrict__ Wg_bf, unsigned short* __restrict__ Wf_bf,
              float* __restrict__ wv, float* __restrict__ wu, float* __restrict__ c0,
              unsigned short* __restrict__ Mhi, unsigned short* __restrict__ Mlo,
              float* __restrict__ U,
              unsigned short* __restrict__ zfT_hi, unsigned short* __restrict__ zfT_lo)
{
    __shared__ float T[64][65];
    const int bx = blockIdx.x, tid = threadIdx.x;

    if (bx < 512) {
        int i = bx * 256 + tid;
        if (i < C * C) Wg_bf[i] = f2bf(Wg[i]);
        if (i < C * 2 * C) Wf_bf[i] = f2bf(Wf[i]);
        return;
    }
    if (bx == 512) {
        float a = 0.f, b = 0.f;
        for (int o = 0; o < C; ++o) {
            a += Wq[o * C + tid] * bs[o];
            b += Ws[o * C + tid] * bq[o];
        }
        wv[tid] = a;
        wu[tid] = b;
        if (tid == 0) {
            float c = 0.f;
            for (int o = 0; o < C; ++o) c += bq[o] * bs[o];
            c0[0] = c;
        }
        return;
    }
    if (bx < 529) {
        const int t  = bx - 513;
        const int j0 = (t & 3) * 64, i0 = (t >> 2) * 64;
        const int tx = tid & 15, ty = tid >> 4;
        float (*Qs)[65] = (float(*)[65])&T[0][0];
        float (*Ss)[65] = (float(*)[65])&T[16][0];
        float acc[4][4] = {};

        for (int kc = 0; kc < C; kc += 16) {
            #pragma unroll
            for (int i = 0; i < 4; ++i) {
                int e = tid + 256 * i;
                int k = e >> 6, col = e & 63;
                Qs[k][col] = Wq[(size_t)(kc + k) * C + i0 + col];
                Ss[k][col] = Ws[(size_t)(kc + k) * C + j0 + col];
            }
            __syncthreads();
            #pragma unroll
            for (int k = 0; k < 16; ++k) {
                float a[4], bv[4];
                #pragma unroll
                for (int i = 0; i < 4; ++i) a[i] = Qs[k][ty * 4 + i];
                #pragma unroll
                for (int j = 0; j < 4; ++j) bv[j] = Ss[k][tx * 4 + j];
                #pragma unroll
                for (int i = 0; i < 4; ++i)
                    #pragma unroll
                    for (int j = 0; j < 4; ++j)
                        acc[i][j] = fmaf(a[i], bv[j], acc[i][j]);
            }
            __syncthreads();
        }
        #pragma unroll
        for (int i = 0; i < 4; ++i)
            #pragma unroll
            for (int j = 0; j < 4; ++j) {
                float v = acc[i][j];
                unsigned short h = f2bf(v);
                size_t idx = (size_t)(i0 + ty * 4 + i) * C + j0 + tx * 4 + j;
                Mhi[idx] = h;
                Mlo[idx] = f2bf(v - bf2f(h));
            }
        return;
    }
    if (bx < 657) {
        const int b = bx - 529, m = tid;
        if (m >= NzP) return;
        float s = 0.f;
        if (m < Nz) {
            const float* zb = zf + (size_t)b * C * Nz + m;
            float s0 = 0.f, s1 = 0.f, s2 = 0.f, s3 = 0.f;
            for (int c = 0; c < C; c += 4) {
                s0 += wu[c]     * zb[(size_t)c * Nz];
                s1 += wu[c + 1] * zb[(size_t)(c + 1) * Nz];
                s2 += wu[c + 2] * zb[(size_t)(c + 2) * Nz];
                s3 += wu[c + 3] * zb[(size_t)(c + 3) * Nz];
            }
            s = (s0 + s1) + (s2 + s3) + c0[0];
        }
        U[(size_t)b * NzP + m] = s;
        return;
    }
    {
        const int t  = bx - 657;
        const int n0 = (t % 3) * 64;
        const int c0v = ((t / 3) & 3) * 64;
        const int b  = t / 12;
        const float* Xb = zf + ((size_t)b * C + c0v) * Nz;
        #pragma unroll
        for (int i = 0; i < 16; ++i) {
            int e = tid + 256 * i;
            int c = e >> 6, n = e & 63;
            T[c][n] = (n0 + n < Nz) ? Xb[(size_t)c * Nz + n0 + n] : 0.f;
        }
        __syncthreads();
        #pragma unroll
        for (int i = 0; i < 16; ++i) {
            int e = tid + 256 * i;
            int n = e >> 6, c = e & 63;
            if (n0 + n < Nz) {
                float v = T[c][n];
                unsigned short h = f2bf(v);
                size_t idx = ((size_t)b * Nz + n0 + n) * C + c0v + c;
                zfT_hi[idx] = h;
                zfT_lo[idx] = f2bf(v - bf2f(h));
            }
        }
    }
}

// ---------------------------------------------------------------------------
// z_gemm: zq' (split) + zf_g (plain), shared B staging (unchanged).
// ---------------------------------------------------------------------------
__global__ __launch_bounds__(256)
void z_gemm(const unsigned short* __restrict__ Mhi,
            const unsigned short* __restrict__ Mlo,
            const unsigned short* __restrict__ Wg,
            const unsigned short* __restrict__ Bhi,
            const unsigned short* __restrict__ Blo,
            const float* __restrict__ wv,
            const float* __restrict__ bg, const float* __restrict__ g_gamma,
            const float* __restrict__ g_beta, const float* __restrict__ g_mean,
            const float* __restrict__ g_var,
            unsigned short* __restrict__ Yqh, unsigned short* __restrict__ Yql,
            unsigned short* __restrict__ Yg)
{
    __shared__ unsigned short Ah[64][40], Al[64][40], Ag[64][40];
    __shared__ unsigned short Bh[64][40], Bl[64][40];

    const int b   = blockIdx.z;
    const int n0  = blockIdx.x * 64;
    const int o0  = blockIdx.y * 64;
    const int tid = threadIdx.x;
    const int lane = tid & 63, wid = tid >> 6;
    const int wr = wid >> 1, wc = wid & 1;

    const unsigned short* Bhb = Bhi + (size_t)b * Nz * C;
    const unsigned short* Blb = Blo + (size_t)b * Nz * C;

    f32x4 accq[2][2], accg[2][2];
    #pragma unroll
    for (int i = 0; i < 2; ++i)
        #pragma unroll
        for (int j = 0; j < 2; ++j)
            #pragma unroll
            for (int e = 0; e < 4; ++e) { accq[i][j][e] = 0.f; accg[i][j][e] = 0.f; }

    const int srow = tid >> 2, sseg = tid & 3;
    const int lr = lane & 15, lk = (lane >> 4) * 8;

    for (int kc = 0; kc < C; kc += 32) {
        const int gk = kc + sseg * 8;
        *(int4*)&Ah[srow][sseg * 8] = *(const int4*)&Mhi[(size_t)(o0 + srow) * C + gk];
        *(int4*)&Al[srow][sseg * 8] = *(const int4*)&Mlo[(size_t)(o0 + srow) * C + gk];
        *(int4*)&Ag[srow][sseg * 8] = *(const int4*)&Wg[(size_t)(o0 + srow) * C + gk];

        const int gn = n0 + srow;
        int4 bv = make_int4(0, 0, 0, 0), blv = make_int4(0, 0, 0, 0);
        if (gn < Nz) {
            bv  = *(const int4*)&Bhb[(size_t)gn * C + gk];
            blv = *(const int4*)&Blb[(size_t)gn * C + gk];
        }
        *(int4*)&Bh[srow][sseg * 8] = bv;
        *(int4*)&Bl[srow][sseg * 8] = blv;
        __syncthreads();

        bf16x8 ah[2], al[2], ag[2], bh[2], bl[2];
        #pragma unroll
        for (int i = 0; i < 2; ++i) {
            ah[i] = *(const bf16x8*)&Ah[wr * 32 + i * 16 + lr][lk];
            al[i] = *(const bf16x8*)&Al[wr * 32 + i * 16 + lr][lk];
            ag[i] = *(const bf16x8*)&Ag[wr * 32 + i * 16 + lr][lk];
            bh[i] = *(const bf16x8*)&Bh[wc * 32 + i * 16 + lr][lk];
            bl[i] = *(const bf16x8*)&Bl[wc * 32 + i * 16 + lr][lk];
        }
        #pragma unroll
        for (int i = 0; i < 2; ++i)
            #pragma unroll
            for (int j = 0; j < 2; ++j) {
                accq[i][j] = __builtin_amdgcn_mfma_f32_16x16x32_bf16(al[i], bh[j], accq[i][j], 0, 0, 0);
                accq[i][j] = __builtin_amdgcn_mfma_f32_16x16x32_bf16(ah[i], bl[j], accq[i][j], 0, 0, 0);
                accq[i][j] = __builtin_amdgcn_mfma_f32_16x16x32_bf16(ah[i], bh[j], accq[i][j], 0, 0, 0);
                accg[i][j] = __builtin_amdgcn_mfma_f32_16x16x32_bf16(ag[i], bh[j], accg[i][j], 0, 0, 0);
            }
        __syncthreads();
    }

    const int lg = lane >> 4;
    #pragma unroll
    for (int i = 0; i < 2; ++i) {
        const int ob = o0 + wr * 32 + i * 16 + lg * 4;
        float bi[4], inv[4], sh[4], bgi[4];
        #pragma unroll
        for (int r = 0; r < 4; ++r) {
            int o = ob + r;
            bi[r] = wv[o];
            float iv = g_gamma[o] * rsqrtf(g_var[o] + EPS);
            inv[r] = iv; sh[r] = g_beta[o] - g_mean[o] * iv; bgi[r] = bg[o];
        }
        #pragma unroll
        for (int j = 0; j < 2; ++j) {
            const int gn = n0 + wc * 32 + j * 16 + lr;
            uint2 ph = make_uint2(0, 0), pl = make_uint2(0, 0), pg = make_uint2(0, 0);
            if (gn < Nz) {
                unsigned short h[4], l[4], g[4];
                #pragma unroll
                for (int r = 0; r < 4; ++r) {
                    float v = accq[i][j][r] + bi[r];
                    h[r] = f2bf(v);
                    l[r] = f2bf(v - bf2f(h[r]));
                    g[r] = f2bf(fmaxf(fmaf(accg[i][j][r] + bgi[r], inv[r], sh[r]), 0.f));
                }
                ph.x = (unsigned)h[0] | ((unsigned)h[1] << 16);
                ph.y = (unsigned)h[2] | ((unsigned)h[3] << 16);
                pl.x = (unsigned)l[0] | ((unsigned)l[1] << 16);
                pl.y = (unsigned)l[2] | ((unsigned)l[3] << 16);
                pg.x = (unsigned)g[0] | ((unsigned)g[1] << 16);
                pg.y = (unsigned)g[2] | ((unsigned)g[3] << 16);
            }
            size_t idx = ((size_t)b * NzP + gn) * C + ob;
            *(uint2*)&Yqh[idx] = ph;
            *(uint2*)&Yql[idx] = pl;
            *(uint2*)&Yg[idx]  = pg;
        }
    }
}

// ---------------------------------------------------------------------------
// zg2 = Wf1 . zf_g  -> [b][O][Nout] bf16 (unchanged)
// ---------------------------------------------------------------------------
__global__ __launch_bounds__(256)
void zg2_gemm(const unsigned short* __restrict__ A, int aLd,
              const unsigned short* __restrict__ B1,
              unsigned short* __restrict__ Y, int N, int Nout, int K, int O)
{
    __shared__ unsigned short As[64][40];
    __shared__ unsigned short Bs[64][40];

    const int b   = blockIdx.z;
    const int n0  = blockIdx.x * 64;
    const int o0  = blockIdx.y * 64;
    const int tid = threadIdx.x;
    const int lane = tid & 63, wid = tid >> 6;
    const int wr = wid >> 1, wc = wid & 1;

    const unsigned short* B1b = B1 + (size_t)b * N * K;

    f32x4 acc[2][2];
    #pragma unroll
    for (int i = 0; i < 2; ++i)
        #pragma unroll
        for (int j = 0; j < 2; ++j)
            #pragma unroll
            for (int e = 0; e < 4; ++e) acc[i][j][e] = 0.f;

    const int srow = tid >> 2, sseg = tid & 3;
    const int lr = lane & 15, lk = (lane >> 4) * 8;

    for (int kc = 0; kc < K; kc += 32) {
        const int gk = kc + sseg * 8;
        *(int4*)&As[srow][sseg * 8] = *(const int4*)&A[(size_t)(o0 + srow) * aLd + gk];

        const int gn = n0 + srow;
        int4 bv = make_int4(0, 0, 0, 0);
        if (gn < N) bv = *(const int4*)&B1b[(size_t)gn * K + gk];
        *(int4*)&Bs[srow][sseg * 8] = bv;
        __syncthreads();

        bf16x8 a0 = *(const bf16x8*)&As[wr * 32 +      lr][lk];
        bf16x8 a1 = *(const bf16x8*)&As[wr * 32 + 16 + lr][lk];
        bf16x8 b0 = *(const bf16x8*)&Bs[wc * 32 +      lr][lk];
        bf16x8 b1 = *(const bf16x8*)&Bs[wc * 32 + 16 + lr][lk];

        acc[0][0] = __builtin_amdgcn_mfma_f32_16x16x32_bf16(a0, b0, acc[0][0], 0, 0, 0);
        acc[0][1] = __builtin_amdgcn_mfma_f32_16x16x32_bf16(a0, b1, acc[0][1], 0, 0, 0);
        acc[1][0] = __builtin_amdgcn_mfma_f32_16x16x32_bf16(a1, b0, acc[1][0], 0, 0, 0);
        acc[1][1] = __builtin_amdgcn_mfma_f32_16x16x32_bf16(a1, b1, acc[1][1], 0, 0, 0);
        __syncthreads();
    }

    const int lg = lane >> 4;
    #pragma unroll
    for (int i = 0; i < 2; ++i) {
        const int ob = o0 + wr * 32 + i * 16 + lg * 4;
        #pragma unroll
        for (int j = 0; j < 2; ++j) {
            const int gn = n0 + wc * 32 + j * 16 + lr;
            if (gn < Nout) {
                #pragma unroll
                for (int r = 0; r < 4; ++r)
                    Y[((size_t)b * O + ob + r) * Nout + gn] =
                        (gn < N) ? f2bf(acc[i][j][r]) : (unsigned short)0;
            }
        }
    }
}

// ---------------------------------------------------------------------------
// X-side megakernel v3:
//  sim : reg-prefetch next chunk during MFMA; XF-hi accumulates into a
//        persistent XFfull[64][264] tile (reused by G — no G staging at all).
//  sparsemax -> Ssc (overlays dead Bz region)
//  G   : A=Wg direct-global, B=XFfull LDS — ZERO barriers
//  XG  : bn_relu(G) XOR-swizzled, overlays dead XFfull
//  P1  : A=zg2 direct, B=Ssc LDS — no barriers
//  P2  : A=Wf2 direct, B=XG LDS — no barriers
// LDS 74,752 B (2 blocks/CU).
// ---------------------------------------------------------------------------
#define XGIDX(n, o) ((((n) << 8) + (o)) ^ (((n) & 7) << 3))

__global__ __launch_bounds__(256)
void mega_x(const float* __restrict__ Xf,
            const unsigned short* __restrict__ Zqh,   // [b][192][256]
            const unsigned short* __restrict__ Zql,
            const unsigned short* __restrict__ Wg,    // [256][256]
            const unsigned short* __restrict__ Zg2,   // [b][256][192]
            const unsigned short* __restrict__ Wf2,   // [256][512] base+256
            const float* __restrict__ U,              // [b][192]
            const float* __restrict__ bg, const float* __restrict__ g_gamma,
            const float* __restrict__ g_beta, const float* __restrict__ g_mean,
            const float* __restrict__ g_var,
            const float* __restrict__ bf, const float* __restrict__ f_gamma,
            const float* __restrict__ f_beta, const float* __restrict__ f_mean,
            const float* __restrict__ f_var,
            float* __restrict__ out)
{
    __shared__ __attribute__((aligned(16))) char pool[74752];
    __shared__ float Us[192];

    unsigned short* XFfull = (unsigned short*)(pool);          // [64][264] hi (sim A + G B)
    unsigned short* XG     = (unsigned short*)(pool);          // [64][256] swz (post-G, overlays XFfull)
    unsigned short* Bzh    = (unsigned short*)(pool + 33792);  // [192][40]
    unsigned short* Bzl    = (unsigned short*)(pool + 49152);  // [192][40]
    unsigned short* Ssc    = (unsigned short*)(pool + 33792);  // [64][200] (post-sim, overlays Bz)
    unsigned short* XFl    = (unsigned short*)(pool + 64512);  // 2x[64][40] lo dbuf

    // XCD-aware swizzle: 1280 blocks, 1280 % 8 == 0 -> bijective
    const int g0  = blockIdx.z * gridDim.x + blockIdx.x;
    const int rid = (g0 & 7) * 160 + (g0 >> 3);
    const int b   = rid / 10;
    const int n0  = (rid % 10) * 64;

    const int tid = threadIdx.x;
    const int lane = tid & 63, w = tid >> 6;
    const int lr = lane & 15, lg = lane >> 4, lk = lg * 8;
    const int brow = tid >> 2, bseg = tid & 3;

    const unsigned short* Zqhb = Zqh + (size_t)b * NzP * C;
    const unsigned short* Zqlb = Zql + (size_t)b * NzP * C;
    const unsigned short* Zg2b = Zg2 + (size_t)b * C * NzP;

    if (tid < 192) Us[tid] = U[(size_t)b * NzP + tid];

    const int gnA = min(n0 + brow, Nx - 1);    // staging row (clamped)

    // ================= sim phase (reg-prefetch pipeline) =================
    {
        f32x4 sacc[12];
        #pragma unroll
        for (int j = 0; j < 12; ++j)
            #pragma unroll
            for (int e = 0; e < 4; ++e) sacc[j][e] = 0.f;

        // stage chunk 0 directly
        {
            const float* src = Xf + ((size_t)b * C + bseg * 8) * Nx + gnA;
            unsigned short h[8], l[8];
            #pragma unroll
            for (int e = 0; e < 8; ++e) {
                float v = src[(size_t)e * Nx];
                h[e] = f2bf(v);
                l[e] = f2bf(v - bf2f(h[e]));
            }
            uint4 ph, pl;
            ph.x = (unsigned)h[0] | ((unsigned)h[1] << 16);
            ph.y = (unsigned)h[2] | ((unsigned)h[3] << 16);
            ph.z = (unsigned)h[4] | ((unsigned)h[5] << 16);
            ph.w = (unsigned)h[6] | ((unsigned)h[7] << 16);
            pl.x = (unsigned)l[0] | ((unsigned)l[1] << 16);
            pl.y = (unsigned)l[2] | ((unsigned)l[3] << 16);
            pl.z = (unsigned)l[4] | ((unsigned)l[5] << 16);
            pl.w = (unsigned)l[6] | ((unsigned)l[7] << 16);
            *(uint4*)&XFfull[brow * 264 + bseg * 8] = ph;
            *(uint4*)&XFl[brow * 40 + bseg * 8] = pl;
            #pragma unroll
            for (int i = 0; i < 3; ++i) {
                const int slot = tid + 256 * i;
                const int r = slot >> 2, s = slot & 3;
                *(int4*)&Bzh[r * 40 + s * 8] = *(const int4*)&Zqhb[(size_t)r * C + s * 8];
                *(int4*)&Bzl[r * 40 + s * 8] = *(const int4*)&Zqlb[(size_t)r * C + s * 8];
            }
        }
        __syncthreads();

        for (int c = 0; c < 8; ++c) {
            const int kc = c * 32;
            // prefetch chunk c+1 into registers (loads overlap the MFMAs below)
            float xfr[8];
            int4 pzh[3], pzl[3];
            if (c < 7) {
                const int kc1 = kc + 32;
                const float* src = Xf + ((size_t)b * C + kc1 + bseg * 8) * Nx + gnA;
                #pragma unroll
                for (int e = 0; e < 8; ++e) xfr[e] = src[(size_t)e * Nx];
                #pragma unroll
                for (int i = 0; i < 3; ++i) {
                    const int slot = tid + 256 * i;
                    const int r = slot >> 2, s = slot & 3;
                    pzh[i] = *(const int4*)&Zqhb[(size_t)r * C + kc1 + s * 8];
                    pzl[i] = *(const int4*)&Zqlb[(size_t)r * C + kc1 + s * 8];
                }
            }

            bf16x8 a0h = *(const bf16x8*)&XFfull[(w * 16 + lr) * 264 + kc + lk];
            bf16x8 a0l = *(const bf16x8*)&XFl[(c & 1) * 2560 + (w * 16 + lr) * 40 + lk];
            #pragma unroll
            for (int j = 0; j < 12; ++j) {
                bf16x8 bh = *(const bf16x8*)&Bzh[(j * 16 + lr) * 40 + lk];
                bf16x8 bl = *(const bf16x8*)&Bzl[(j * 16 + lr) * 40 + lk];
                sacc[j] = __builtin_amdgcn_mfma_f32_16x16x32_bf16(a0l, bh, sacc[j], 0, 0, 0);
                sacc[j] = __builtin_amdgcn_mfma_f32_16x16x32_bf16(a0h, bl, sacc[j], 0, 0, 0);
                sacc[j] = __builtin_amdgcn_mfma_f32_16x16x32_bf16(a0h, bh, sacc[j], 0, 0, 0);
            }
            __syncthreads();   // all reads of Bz/XFl chunk c done

            if (c < 7) {
                unsigned short h[8], l[8];
                #pragma unroll
                for (int e = 0; e < 8; ++e) {
                    h[e] = f2bf(xfr[e]);
                    l[e] = f2bf(xfr[e] - bf2f(h[e]));
                }
                uint4 ph, pl;
                ph.x = (unsigned)h[0] | ((unsigned)h[1] << 16);
                ph.y = (unsigned)h[2] | ((unsigned)h[3] << 16);
                ph.z = (unsigned)h[4] | ((unsigned)h[5] << 16);
                ph.w = (unsigned)h[6] | ((unsigned)h[7] << 16);
                pl.x = (unsigned)l[0] | ((unsigned)l[1] << 16);
                pl.y = (unsigned)l[2] | ((unsigned)l[3] << 16);
                pl.z = (unsigned)l[4] | ((unsigned)l[5] << 16);
                pl.w = (unsigned)l[6] | ((unsigned)l[7] << 16);
                *(uint4*)&XFfull[brow * 264 + (kc + 32) + bseg * 8] = ph;
                *(uint4*)&XFl[((c + 1) & 1) * 2560 + brow * 40 + bseg * 8] = pl;
                #pragma unroll
                for (int i = 0; i < 3; ++i) {
                    const int slot = tid + 256 * i;
                    const int r = slot >> 2, s = slot & 3;
                    *(int4*)&Bzh[r * 40 + s * 8] = pzh[i];
                    *(int4*)&Bzl[r * 40 + s * 8] = pzl[i];
                }
                __syncthreads();
            }
        }

        // add u[m], mask padded m
        #pragma unroll
        for (int j = 0; j < 12; ++j) {
            const int m = j * 16 + lr;
            const float uv = Us[m];
            const bool bad = (m >= Nz);
            #pragma unroll
            for (int q = 0; q < 4; ++q)
                sacc[j][q] = bad ? -1e30f : (sacc[j][q] + uv);
        }

        f32x4 mx = sacc[0];
        #pragma unroll
        for (int j = 1; j < 12; ++j)
            #pragma unroll
            for (int q = 0; q < 4; ++q) mx[q] = fmaxf(mx[q], sacc[j][q]);
        #pragma unroll
        for (int off = 1; off < 16; off <<= 1)
            #pragma unroll
            for (int q = 0; q < 4; ++q) mx[q] = fmaxf(mx[q], __shfl_xor(mx[q], off));

        f32x4 tau;
        #pragma unroll
        for (int q = 0; q < 4; ++q) tau[q] = mx[q] - 1.0f;

        for (int it = 0; it < 16; ++it) {
            f32x4 s, cnt;
            #pragma unroll
            for (int q = 0; q < 4; ++q) { s[q] = 0.f; cnt[q] = 0.f; }
            #pragma unroll
            for (int j = 0; j < 12; ++j)
                #pragma unroll
                for (int q = 0; q < 4; ++q)
                    if (sacc[j][q] > tau[q]) { s[q] += sacc[j][q]; cnt[q] += 1.f; }
            #pragma unroll
            for (int off = 1; off < 16; off <<= 1)
                #pragma unroll
                for (int q = 0; q < 4; ++q) {
                    s[q]   += __shfl_xor(s[q], off);
                    cnt[q] += __shfl_xor(cnt[q], off);
                }
            bool adv = false;
            #pragma unroll
            for (int q = 0; q < 4; ++q) {
                float nt = (s[q] - 1.0f) / cnt[q];
                if (nt > tau[q]) { tau[q] = nt; adv = true; }
            }
            if (!__any(adv ? 1 : 0)) break;
        }

        // scores -> Ssc (overlays Bz; last Bz read was before chunk-7 barrier)
        #pragma unroll
        for (int q = 0; q < 4; ++q) {
            const int n = w * 16 + 4 * lg + q;
            #pragma unroll
            for (int j = 0; j < 12; ++j) {
                const int m = j * 16 + lr;
                float sv = (m < Nz) ? fmaxf(sacc[j][q] - tau[q], 0.f) : 0.f;
                Ssc[n * 200 + m] = f2bf(sv);
            }
        }
    }

    // ================= G phase: acc = Wg . xf (A global, B = XFfull LDS,
    // ZERO staging / barriers) =================
    f32x4 acc[4][4];
    #pragma unroll
    for (int i = 0; i < 4; ++i)
        #pragma unroll
        for (int j = 0; j < 4; ++j)
            #pragma unroll
            for (int e = 0; e < 4; ++e) acc[i][j][e] = 0.f;

    #pragma unroll
    for (int c = 0; c < 8; ++c) {
        const int kc = c * 32;
        bf16x8 a[4], bfr[4];
        #pragma unroll
        for (int i = 0; i < 4; ++i)
            a[i] = *(const bf16x8*)&Wg[(size_t)(w * 64 + i * 16 + lr) * C + kc + lk];
        #pragma unroll
        for (int j = 0; j < 4; ++j)
            bfr[j] = *(const bf16x8*)&XFfull[(j * 16 + lr) * 264 + kc + lk];
        #pragma unroll
        for (int i = 0; i < 4; ++i)
            #pragma unroll
            for (int j = 0; j < 4; ++j)
                acc[i][j] = __builtin_amdgcn_mfma_f32_16x16x32_bf16(a[i], bfr[j], acc[i][j], 0, 0, 0);
    }
    __syncthreads();   // all XFfull reads + Ssc writes complete

    // G epilogue: bn_relu -> XG (XOR-swizzled, overlays XFfull)
    #pragma unroll
    for (int i = 0; i < 4; ++i) {
        const int ob = w * 64 + i * 16 + lg * 4;
        float inv[4], sh[4], bi[4];
        #pragma unroll
        for (int r = 0; r < 4; ++r) {
            int o = ob + r;
            float iv = g_gamma[o] * rsqrtf(g_var[o] + EPS);
            inv[r] = iv; sh[r] = g_beta[o] - g_mean[o] * iv; bi[r] = bg[o];
        }
        #pragma unroll
        for (int j = 0; j < 4; ++j) {
            const int n = j * 16 + lr;
            unsigned short h[4];
            #pragma unroll
            for (int r = 0; r < 4; ++r)
                h[r] = f2bf(fmaxf(fmaf(acc[i][j][r] + bi[r], inv[r], sh[r]), 0.f));
            uint2 pk;
            pk.x = (unsigned)h[0] | ((unsigned)h[1] << 16);
            pk.y = (unsigned)h[2] | ((unsigned)h[3] << 16);
            *(uint2*)&XG[XGIDX(n, ob)] = pk;
        }
    }
    #pragma unroll
    for (int i = 0; i < 4; ++i)
        #pragma unroll
        for (int j = 0; j < 4; ++j)
            #pragma unroll
            for (int e = 0; e < 4; ++e) acc[i][j][e] = 0.f;
    __syncthreads();   // XG visible — last barrier of the kernel

    // ================= P1: acc += zg2 . Ssc =================
    #pragma unroll
    for (int c = 0; c < 6; ++c) {
        const int kc = c * 32;
        bf16x8 a[4], bfr[4];
        #pragma unroll
        for (int i = 0; i < 4; ++i)
            a[i] = *(const bf16x8*)&Zg2b[(size_t)(w * 64 + i * 16 + lr) * NzP + kc + lk];
        #pragma unroll
        for (int j = 0; j < 4; ++j)
            bfr[j] = *(const bf16x8*)&Ssc[(j * 16 + lr) * 200 + kc + lk];
        #pragma unroll
        for (int i = 0; i < 4; ++i)
            #pragma unroll
            for (int j = 0; j < 4; ++j)
                acc[i][j] = __builtin_amdgcn_mfma_f32_16x16x32_bf16(a[i], bfr[j], acc[i][j], 0, 0, 0);
    }

    // ================= P2: acc += Wf2 . XG =================
    #pragma unroll
    for (int c = 0; c < 8; ++c) {
        const int kc = c * 32;
        bf16x8 a[4], bfr[4];
        #pragma unroll
        for (int i = 0; i < 4; ++i)
            a[i] = *(const bf16x8*)&Wf2[(size_t)(w * 64 + i * 16 + lr) * 512 + kc + lk];
        #pragma unroll
        for (int j = 0; j < 4; ++j)
            bfr[j] = *(const bf16x8*)&XG[XGIDX(j * 16 + lr, kc + lk)];
        #pragma unroll
        for (int i = 0; i < 4; ++i)
            #pragma unroll
            for (int j = 0; j < 4; ++j)
                acc[i][j] = __builtin_amdgcn_mfma_f32_16x16x32_bf16(a[i], bfr[j], acc[i][j], 0, 0, 0);
    }

    // final epilogue: bn_relu(f) -> out f32 [b][256][Nx]
    #pragma unroll
    for (int i = 0; i < 4; ++i) {
        const int ob = w * 64 + i * 16 + lg * 4;
        float inv[4], sh[4], bi[4];
        #pragma unroll
        for (int r = 0; r < 4; ++r) {
            int o = ob + r;
            float iv = f_gamma[o] * rsqrtf(f_var[o] + EPS);
            inv[r] = iv; sh[r] = f_beta[o] - f_mean[o] * iv; bi[r] = bf[o];
        }
        #pragma unroll
        for (int j = 0; j < 4; ++j) {
            const int gn = n0 + j * 16 + lr;
            if (gn < Nx) {
                #pragma unroll
                for (int r = 0; r < 4; ++r) {
                    float v = fmaxf(fmaf(acc[i][j][r] + bi[r], inv[r], sh[r]), 0.f);
                    out[((size_t)b * C + ob + r) * Nx + gn] = v;
                }
            }
        }
    }
}

// ---------------------------------------------------------------------------
extern "C" void kernel_launch(void* const* d_in, const int* in_sizes, int n_in,
                              void* d_out, int out_size, void* d_ws, size_t ws_size,
                              hipStream_t stream)
{
    const float* zf      = (const float*)d_in[0];
    const float* xf      = (const float*)d_in[1];
    const float* Wq      = (const float*)d_in[2];
    const float* bq      = (const float*)d_in[3];
    const float* Ws_     = (const float*)d_in[4];
    const float* bs      = (const float*)d_in[5];
    const float* Wg      = (const float*)d_in[6];
    const float* bg      = (const float*)d_in[7];
    const float* g_gamma = (const float*)d_in[8];
    const float* g_beta  = (const float*)d_in[9];
    const float* g_mean  = (const float*)d_in[10];
    const float* g_var   = (const float*)d_in[11];
    const float* Wf      = (const float*)d_in[12];
    const float* bf_     = (const float*)d_in[13];
    const float* f_gamma = (const float*)d_in[14];
    const float* f_beta  = (const float*)d_in[15];
    const float* f_mean  = (const float*)d_in[16];
    const float* f_var   = (const float*)d_in[17];
    float* out = (float*)d_out;

    typedef unsigned short u16;
    char* ws = (char*)d_ws;
    u16*   zfT_hi = (u16*)(ws);                   //  11,075,584
    u16*   zfT_lo = (u16*)(ws +  11075584);       //  11,075,584
    u16*   zqT_hi = (u16*)(ws +  22151168);       //  12,582,912
    u16*   zqT_lo = (u16*)(ws +  34734080);       //  12,582,912
    u16*   zf_gT  = (u16*)(ws +  47316992);       //  12,582,912
    u16*   zg2    = (u16*)(ws +  59899904);       //  12,582,912
    float* U      = (float*)(ws +  72482816);     //      98,304
    u16*   Mhi    = (u16*)(ws +  72581120);       //     131,072
    u16*   Mlo    = (u16*)(ws +  72712192);       //     131,072
    u16*   Wg_bf  = (u16*)(ws +  72843264);       //     131,072
    u16*   Wf_bf  = (u16*)(ws +  72974336);       //     262,144
    float* wv     = (float*)(ws +  73236480);     //       1,024
    float* wu     = (float*)(ws +  73237504);     //       1,024
    float* c0     = (float*)(ws +  73238528);     //         256

    dim3 blk(256);
    const int gx_x = (Nx + 63) / 64;   // 10
    const int gx_z = NzP / 64;         // 3

    prep_all<<<dim3(2193), blk, 0, stream>>>(
        zf, Wq, bq, Ws_, bs, Wg, Wf,
        Wg_bf, Wf_bf, wv, wu, c0, Mhi, Mlo, U, zfT_hi, zfT_lo);

    z_gemm<<<dim3(gx_z, C / 64, Bb), blk, 0, stream>>>(
        Mhi, Mlo, Wg_bf, zfT_hi, zfT_lo, wv,
        bg, g_gamma, g_beta, g_mean, g_var,
        zqT_hi, zqT_lo, zf_gT);

    zg2_gemm<<<dim3(gx_z, C / 64, Bb), blk, 0, stream>>>(
        Wf_bf, 2 * C, zf_gT, zg2, NzP, NzP, C, C);

    mega_x<<<dim3(gx_x, 1, Bb), blk, 0, stream>>>(
        xf, zqT_hi, zqT_lo, Wg_bf, zg2, Wf_bf + C, U,
        bg, g_gamma, g_beta, g_mean, g_var,
        bf_, f_gamma, f_beta, f_mean, f_var, out);
}

// Round 16
// 199.020 us; speedup vs baseline: 1.1340x; 1.1340x over previous
//
#include <hip/hip_runtime.h>
#include <math.h>

#define EPS 1e-5f

constexpr int Bb  = 128;
constexpr int C   = 256;
constexpr int Nz  = 169;   // 13*13
constexpr int Nx  = 625;   // 25*25
constexpr int NzP = 192;   // Nz padded (zero-filled)

typedef __bf16 bf16x8 __attribute__((ext_vector_type(8)));
typedef float  f32x4  __attribute__((ext_vector_type(4)));

__device__ __forceinline__ unsigned short f2bf(float f) {
    union { float f; unsigned u; } x; x.f = f;
    unsigned r = x.u + 0x7FFFu + ((x.u >> 16) & 1u);   // RNE
    return (unsigned short)(r >> 16);
}
__device__ __forceinline__ float bf2f(unsigned short h) {
    union { unsigned u; float f; } x; x.u = ((unsigned)h) << 16;
    return x.f;
}

// ---------------------------------------------------------------------------
// prep_all: all mutually-independent precomputes in ONE launch (unchanged).
// ---------------------------------------------------------------------------
__global__ __launch_bounds__(256)
void prep_all(const float* __restrict__ zf,
              const float* __restrict__ Wq, const float* __restrict__ bq,
              const float* __restrict__ Ws, const float* __restrict__ bs,
              const float* __restrict__ Wg, const float* __restrict__ Wf,
              unsigned short* __restrict__ Wg_bf, unsigned short* __restrict__ Wf_bf,
              float* __restrict__ wv, float* __restrict__ wu, float* __restrict__ c0,
              unsigned short* __restrict__ Mhi, unsigned short* __restrict__ Mlo,
              float* __restrict__ U,
              unsigned short* __restrict__ zfT_hi, unsigned short* __restrict__ zfT_lo)
{
    __shared__ float T[64][65];
    const int bx = blockIdx.x, tid = threadIdx.x;

    if (bx < 512) {
        int i = bx * 256 + tid;
        if (i < C * C) Wg_bf[i] = f2bf(Wg[i]);
        if (i < C * 2 * C) Wf_bf[i] = f2bf(Wf[i]);
        return;
    }
    if (bx == 512) {
        float a = 0.f, b = 0.f;
        for (int o = 0; o < C; ++o) {
            a += Wq[o * C + tid] * bs[o];
            b += Ws[o * C + tid] * bq[o];
        }
        wv[tid] = a;
        wu[tid] = b;
        if (tid == 0) {
            float c = 0.f;
            for (int o = 0; o < C; ++o) c += bq[o] * bs[o];
            c0[0] = c;
        }
        return;
    }
    if (bx < 529) {
        const int t  = bx - 513;
        const int j0 = (t & 3) * 64, i0 = (t >> 2) * 64;
        const int tx = tid & 15, ty = tid >> 4;
        float (*Qs)[65] = (float(*)[65])&T[0][0];
        float (*Ss)[65] = (float(*)[65])&T[16][0];
        float acc[4][4] = {};

        for (int kc = 0; kc < C; kc += 16) {
            #pragma unroll
            for (int i = 0; i < 4; ++i) {
                int e = tid + 256 * i;
                int k = e >> 6, col = e & 63;
                Qs[k][col] = Wq[(size_t)(kc + k) * C + i0 + col];
                Ss[k][col] = Ws[(size_t)(kc + k) * C + j0 + col];
            }
            __syncthreads();
            #pragma unroll
            for (int k = 0; k < 16; ++k) {
                float a[4], bv[4];
                #pragma unroll
                for (int i = 0; i < 4; ++i) a[i] = Qs[k][ty * 4 + i];
                #pragma unroll
                for (int j = 0; j < 4; ++j) bv[j] = Ss[k][tx * 4 + j];
                #pragma unroll
                for (int i = 0; i < 4; ++i)
                    #pragma unroll
                    for (int j = 0; j < 4; ++j)
                        acc[i][j] = fmaf(a[i], bv[j], acc[i][j]);
            }
            __syncthreads();
        }
        #pragma unroll
        for (int i = 0; i < 4; ++i)
            #pragma unroll
            for (int j = 0; j < 4; ++j) {
                float v = acc[i][j];
                unsigned short h = f2bf(v);
                size_t idx = (size_t)(i0 + ty * 4 + i) * C + j0 + tx * 4 + j;
                Mhi[idx] = h;
                Mlo[idx] = f2bf(v - bf2f(h));
            }
        return;
    }
    if (bx < 657) {
        const int b = bx - 529, m = tid;
        if (m >= NzP) return;
        float s = 0.f;
        if (m < Nz) {
            const float* zb = zf + (size_t)b * C * Nz + m;
            float s0 = 0.f, s1 = 0.f, s2 = 0.f, s3 = 0.f;
            for (int c = 0; c < C; c += 4) {
                s0 += wu[c]     * zb[(size_t)c * Nz];
                s1 += wu[c + 1] * zb[(size_t)(c + 1) * Nz];
                s2 += wu[c + 2] * zb[(size_t)(c + 2) * Nz];
                s3 += wu[c + 3] * zb[(size_t)(c + 3) * Nz];
            }
            s = (s0 + s1) + (s2 + s3) + c0[0];
        }
        U[(size_t)b * NzP + m] = s;
        return;
    }
    {
        const int t  = bx - 657;
        const int n0 = (t % 3) * 64;
        const int c0v = ((t / 3) & 3) * 64;
        const int b  = t / 12;
        const float* Xb = zf + ((size_t)b * C + c0v) * Nz;
        #pragma unroll
        for (int i = 0; i < 16; ++i) {
            int e = tid + 256 * i;
            int c = e >> 6, n = e & 63;
            T[c][n] = (n0 + n < Nz) ? Xb[(size_t)c * Nz + n0 + n] : 0.f;
        }
        __syncthreads();
        #pragma unroll
        for (int i = 0; i < 16; ++i) {
            int e = tid + 256 * i;
            int n = e >> 6, c = e & 63;
            if (n0 + n < Nz) {
                float v = T[c][n];
                unsigned short h = f2bf(v);
                size_t idx = ((size_t)b * Nz + n0 + n) * C + c0v + c;
                zfT_hi[idx] = h;
                zfT_lo[idx] = f2bf(v - bf2f(h));
            }
        }
    }
}

// ---------------------------------------------------------------------------
// z_gemm: zq' (split) + zf_g (plain), shared B staging (unchanged).
// ---------------------------------------------------------------------------
__global__ __launch_bounds__(256)
void z_gemm(const unsigned short* __restrict__ Mhi,
            const unsigned short* __restrict__ Mlo,
            const unsigned short* __restrict__ Wg,
            const unsigned short* __restrict__ Bhi,
            const unsigned short* __restrict__ Blo,
            const float* __restrict__ wv,
            const float* __restrict__ bg, const float* __restrict__ g_gamma,
            const float* __restrict__ g_beta, const float* __restrict__ g_mean,
            const float* __restrict__ g_var,
            unsigned short* __restrict__ Yqh, unsigned short* __restrict__ Yql,
            unsigned short* __restrict__ Yg)
{
    __shared__ unsigned short Ah[64][40], Al[64][40], Ag[64][40];
    __shared__ unsigned short Bh[64][40], Bl[64][40];

    const int b   = blockIdx.z;
    const int n0  = blockIdx.x * 64;
    const int o0  = blockIdx.y * 64;
    const int tid = threadIdx.x;
    const int lane = tid & 63, wid = tid >> 6;
    const int wr = wid >> 1, wc = wid & 1;

    const unsigned short* Bhb = Bhi + (size_t)b * Nz * C;
    const unsigned short* Blb = Blo + (size_t)b * Nz * C;

    f32x4 accq[2][2], accg[2][2];
    #pragma unroll
    for (int i = 0; i < 2; ++i)
        #pragma unroll
        for (int j = 0; j < 2; ++j)
            #pragma unroll
            for (int e = 0; e < 4; ++e) { accq[i][j][e] = 0.f; accg[i][j][e] = 0.f; }

    const int srow = tid >> 2, sseg = tid & 3;
    const int lr = lane & 15, lk = (lane >> 4) * 8;

    for (int kc = 0; kc < C; kc += 32) {
        const int gk = kc + sseg * 8;
        *(int4*)&Ah[srow][sseg * 8] = *(const int4*)&Mhi[(size_t)(o0 + srow) * C + gk];
        *(int4*)&Al[srow][sseg * 8] = *(const int4*)&Mlo[(size_t)(o0 + srow) * C + gk];
        *(int4*)&Ag[srow][sseg * 8] = *(const int4*)&Wg[(size_t)(o0 + srow) * C + gk];

        const int gn = n0 + srow;
        int4 bv = make_int4(0, 0, 0, 0), blv = make_int4(0, 0, 0, 0);
        if (gn < Nz) {
            bv  = *(const int4*)&Bhb[(size_t)gn * C + gk];
            blv = *(const int4*)&Blb[(size_t)gn * C + gk];
        }
        *(int4*)&Bh[srow][sseg * 8] = bv;
        *(int4*)&Bl[srow][sseg * 8] = blv;
        __syncthreads();

        bf16x8 ah[2], al[2], ag[2], bh[2], bl[2];
        #pragma unroll
        for (int i = 0; i < 2; ++i) {
            ah[i] = *(const bf16x8*)&Ah[wr * 32 + i * 16 + lr][lk];
            al[i] = *(const bf16x8*)&Al[wr * 32 + i * 16 + lr][lk];
            ag[i] = *(const bf16x8*)&Ag[wr * 32 + i * 16 + lr][lk];
            bh[i] = *(const bf16x8*)&Bh[wc * 32 + i * 16 + lr][lk];
            bl[i] = *(const bf16x8*)&Bl[wc * 32 + i * 16 + lr][lk];
        }
        #pragma unroll
        for (int i = 0; i < 2; ++i)
            #pragma unroll
            for (int j = 0; j < 2; ++j) {
                accq[i][j] = __builtin_amdgcn_mfma_f32_16x16x32_bf16(al[i], bh[j], accq[i][j], 0, 0, 0);
                accq[i][j] = __builtin_amdgcn_mfma_f32_16x16x32_bf16(ah[i], bl[j], accq[i][j], 0, 0, 0);
                accq[i][j] = __builtin_amdgcn_mfma_f32_16x16x32_bf16(ah[i], bh[j], accq[i][j], 0, 0, 0);
                accg[i][j] = __builtin_amdgcn_mfma_f32_16x16x32_bf16(ag[i], bh[j], accg[i][j], 0, 0, 0);
            }
        __syncthreads();
    }

    const int lg = lane >> 4;
    #pragma unroll
    for (int i = 0; i < 2; ++i) {
        const int ob = o0 + wr * 32 + i * 16 + lg * 4;
        float bi[4], inv[4], sh[4], bgi[4];
        #pragma unroll
        for (int r = 0; r < 4; ++r) {
            int o = ob + r;
            bi[r] = wv[o];
            float iv = g_gamma[o] * rsqrtf(g_var[o] + EPS);
            inv[r] = iv; sh[r] = g_beta[o] - g_mean[o] * iv; bgi[r] = bg[o];
        }
        #pragma unroll
        for (int j = 0; j < 2; ++j) {
            const int gn = n0 + wc * 32 + j * 16 + lr;
            uint2 ph = make_uint2(0, 0), pl = make_uint2(0, 0), pg = make_uint2(0, 0);
            if (gn < Nz) {
                unsigned short h[4], l[4], g[4];
                #pragma unroll
                for (int r = 0; r < 4; ++r) {
                    float v = accq[i][j][r] + bi[r];
                    h[r] = f2bf(v);
                    l[r] = f2bf(v - bf2f(h[r]));
                    g[r] = f2bf(fmaxf(fmaf(accg[i][j][r] + bgi[r], inv[r], sh[r]), 0.f));
                }
                ph.x = (unsigned)h[0] | ((unsigned)h[1] << 16);
                ph.y = (unsigned)h[2] | ((unsigned)h[3] << 16);
                pl.x = (unsigned)l[0] | ((unsigned)l[1] << 16);
                pl.y = (unsigned)l[2] | ((unsigned)l[3] << 16);
                pg.x = (unsigned)g[0] | ((unsigned)g[1] << 16);
                pg.y = (unsigned)g[2] | ((unsigned)g[3] << 16);
            }
            size_t idx = ((size_t)b * NzP + gn) * C + ob;
            *(uint2*)&Yqh[idx] = ph;
            *(uint2*)&Yql[idx] = pl;
            *(uint2*)&Yg[idx]  = pg;
        }
    }
}

// ---------------------------------------------------------------------------
// zg2 = Wf1 . zf_g  -> [b][O][Nout] bf16 (unchanged)
// ---------------------------------------------------------------------------
__global__ __launch_bounds__(256)
void zg2_gemm(const unsigned short* __restrict__ A, int aLd,
              const unsigned short* __restrict__ B1,
              unsigned short* __restrict__ Y, int N, int Nout, int K, int O)
{
    __shared__ unsigned short As[64][40];
    __shared__ unsigned short Bs[64][40];

    const int b   = blockIdx.z;
    const int n0  = blockIdx.x * 64;
    const int o0  = blockIdx.y * 64;
    const int tid = threadIdx.x;
    const int lane = tid & 63, wid = tid >> 6;
    const int wr = wid >> 1, wc = wid & 1;

    const unsigned short* B1b = B1 + (size_t)b * N * K;

    f32x4 acc[2][2];
    #pragma unroll
    for (int i = 0; i < 2; ++i)
        #pragma unroll
        for (int j = 0; j < 2; ++j)
            #pragma unroll
            for (int e = 0; e < 4; ++e) acc[i][j][e] = 0.f;

    const int srow = tid >> 2, sseg = tid & 3;
    const int lr = lane & 15, lk = (lane >> 4) * 8;

    for (int kc = 0; kc < K; kc += 32) {
        const int gk = kc + sseg * 8;
        *(int4*)&As[srow][sseg * 8] = *(const int4*)&A[(size_t)(o0 + srow) * aLd + gk];

        const int gn = n0 + srow;
        int4 bv = make_int4(0, 0, 0, 0);
        if (gn < N) bv = *(const int4*)&B1b[(size_t)gn * K + gk];
        *(int4*)&Bs[srow][sseg * 8] = bv;
        __syncthreads();

        bf16x8 a0 = *(const bf16x8*)&As[wr * 32 +      lr][lk];
        bf16x8 a1 = *(const bf16x8*)&As[wr * 32 + 16 + lr][lk];
        bf16x8 b0 = *(const bf16x8*)&Bs[wc * 32 +      lr][lk];
        bf16x8 b1 = *(const bf16x8*)&Bs[wc * 32 + 16 + lr][lk];

        acc[0][0] = __builtin_amdgcn_mfma_f32_16x16x32_bf16(a0, b0, acc[0][0], 0, 0, 0);
        acc[0][1] = __builtin_amdgcn_mfma_f32_16x16x32_bf16(a0, b1, acc[0][1], 0, 0, 0);
        acc[1][0] = __builtin_amdgcn_mfma_f32_16x16x32_bf16(a1, b0, acc[1][0], 0, 0, 0);
        acc[1][1] = __builtin_amdgcn_mfma_f32_16x16x32_bf16(a1, b1, acc[1][1], 0, 0, 0);
        __syncthreads();
    }

    const int lg = lane >> 4;
    #pragma unroll
    for (int i = 0; i < 2; ++i) {
        const int ob = o0 + wr * 32 + i * 16 + lg * 4;
        #pragma unroll
        for (int j = 0; j < 2; ++j) {
            const int gn = n0 + wc * 32 + j * 16 + lr;
            if (gn < Nout) {
                #pragma unroll
                for (int r = 0; r < 4; ++r)
                    Y[((size_t)b * O + ob + r) * Nout + gn] =
                        (gn < N) ? f2bf(acc[i][j][r]) : (unsigned short)0;
            }
        }
    }
}

// ---------------------------------------------------------------------------
// X-side megakernel v4 (R14 sim structure + persistent XFfull, NO reg
// prefetch — avoids R15's scratch spill):
//  sim : stage→sync→MFMA→sync per chunk; xf-hi lands in persistent
//        XFfull[64][264]; xf-lo in scratch XFl[64][40].
//  sparsemax -> Ssc (overlays dead Bz region)
//  G   : A=Wg direct-global, B=XFfull LDS — ZERO staging, ZERO barriers
//  XG  : bn_relu(G) XOR-swizzled, overlays dead XFfull
//  P1  : A=zg2 direct, B=Ssc LDS — no barriers
//  P2  : A=Wf2 direct, B=XG LDS — no barriers
// LDS pool 69,632 B -> 2 blocks/CU.
// ---------------------------------------------------------------------------
#define XGIDX(n, o) ((((n) << 8) + (o)) ^ (((n) & 7) << 3))

__global__ __launch_bounds__(256)
void mega_x(const float* __restrict__ Xf,
            const unsigned short* __restrict__ Zqh,   // [b][192][256]
            const unsigned short* __restrict__ Zql,
            const unsigned short* __restrict__ Wg,    // [256][256]
            const unsigned short* __restrict__ Zg2,   // [b][256][192]
            const unsigned short* __restrict__ Wf2,   // [256][512] base+256
            const float* __restrict__ U,              // [b][192]
            const float* __restrict__ bg, const float* __restrict__ g_gamma,
            const float* __restrict__ g_beta, const float* __restrict__ g_mean,
            const float* __restrict__ g_var,
            const float* __restrict__ bf, const float* __restrict__ f_gamma,
            const float* __restrict__ f_beta, const float* __restrict__ f_mean,
            const float* __restrict__ f_var,
            float* __restrict__ out)
{
    __shared__ __attribute__((aligned(16))) char pool[69632];
    __shared__ float Us[192];

    unsigned short* XFfull = (unsigned short*)(pool);          // [64][264] hi (sim A + G B)
    unsigned short* XG     = (unsigned short*)(pool);          // [64][256] swz (post-G)
    unsigned short* Bzh    = (unsigned short*)(pool + 33792);  // [192][40]
    unsigned short* Bzl    = (unsigned short*)(pool + 49152);  // [192][40]
    unsigned short* Ssc    = (unsigned short*)(pool + 33792);  // [64][200] (post-sim)
    unsigned short* XFl    = (unsigned short*)(pool + 64512);  // [64][40] lo scratch

    // XCD-aware swizzle: 1280 blocks, 1280 % 8 == 0 -> bijective
    const int g0  = blockIdx.z * gridDim.x + blockIdx.x;
    const int rid = (g0 & 7) * 160 + (g0 >> 3);
    const int b   = rid / 10;
    const int n0  = (rid % 10) * 64;

    const int tid = threadIdx.x;
    const int lane = tid & 63, w = tid >> 6;
    const int lr = lane & 15, lg = lane >> 4, lk = lg * 8;
    const int brow = tid >> 2, bseg = tid & 3;

    const unsigned short* Zqhb = Zqh + (size_t)b * NzP * C;
    const unsigned short* Zqlb = Zql + (size_t)b * NzP * C;
    const unsigned short* Zg2b = Zg2 + (size_t)b * C * NzP;

    if (tid < 192) Us[tid] = U[(size_t)b * NzP + tid];

    const int gnA = min(n0 + brow, Nx - 1);    // staging row (clamped)

    // ================= sim phase (R14 structure, hi -> XFfull) =============
    {
        f32x4 sacc[12];
        #pragma unroll
        for (int j = 0; j < 12; ++j)
            #pragma unroll
            for (int e = 0; e < 4; ++e) sacc[j][e] = 0.f;

        for (int kc = 0; kc < C; kc += 32) {
            {
                const float* src = Xf + ((size_t)b * C + kc + bseg * 8) * Nx + gnA;
                unsigned short h[8], l[8];
                #pragma unroll
                for (int e = 0; e < 8; ++e) {
                    float v = src[(size_t)e * Nx];
                    h[e] = f2bf(v);
                    l[e] = f2bf(v - bf2f(h[e]));
                }
                uint4 ph, pl;
                ph.x = (unsigned)h[0] | ((unsigned)h[1] << 16);
                ph.y = (unsigned)h[2] | ((unsigned)h[3] << 16);
                ph.z = (unsigned)h[4] | ((unsigned)h[5] << 16);
                ph.w = (unsigned)h[6] | ((unsigned)h[7] << 16);
                pl.x = (unsigned)l[0] | ((unsigned)l[1] << 16);
                pl.y = (unsigned)l[2] | ((unsigned)l[3] << 16);
                pl.z = (unsigned)l[4] | ((unsigned)l[5] << 16);
                pl.w = (unsigned)l[6] | ((unsigned)l[7] << 16);
                *(uint4*)&XFfull[brow * 264 + kc + bseg * 8] = ph;
                *(uint4*)&XFl[brow * 40 + bseg * 8] = pl;
            }
            #pragma unroll
            for (int i = 0; i < 3; ++i) {
                const int slot = tid + 256 * i;
                const int r = slot >> 2, s = slot & 3;
                const int gk = kc + s * 8;
                *(int4*)&Bzh[r * 40 + s * 8] = *(const int4*)&Zqhb[(size_t)r * C + gk];
                *(int4*)&Bzl[r * 40 + s * 8] = *(const int4*)&Zqlb[(size_t)r * C + gk];
            }
            __syncthreads();

            bf16x8 a0h = *(const bf16x8*)&XFfull[(w * 16 + lr) * 264 + kc + lk];
            bf16x8 a0l = *(const bf16x8*)&XFl[(w * 16 + lr) * 40 + lk];
            #pragma unroll
            for (int j = 0; j < 12; ++j) {
                bf16x8 bh = *(const bf16x8*)&Bzh[(j * 16 + lr) * 40 + lk];
                bf16x8 bl = *(const bf16x8*)&Bzl[(j * 16 + lr) * 40 + lk];
                sacc[j] = __builtin_amdgcn_mfma_f32_16x16x32_bf16(a0l, bh, sacc[j], 0, 0, 0);
                sacc[j] = __builtin_amdgcn_mfma_f32_16x16x32_bf16(a0h, bl, sacc[j], 0, 0, 0);
                sacc[j] = __builtin_amdgcn_mfma_f32_16x16x32_bf16(a0h, bh, sacc[j], 0, 0, 0);
            }
            __syncthreads();
        }

        // add u[m], mask padded m
        #pragma unroll
        for (int j = 0; j < 12; ++j) {
            const int m = j * 16 + lr;
            const float uv = Us[m];
            const bool bad = (m >= Nz);
            #pragma unroll
            for (int q = 0; q < 4; ++q)
                sacc[j][q] = bad ? -1e30f : (sacc[j][q] + uv);
        }

        f32x4 mx = sacc[0];
        #pragma unroll
        for (int j = 1; j < 12; ++j)
            #pragma unroll
            for (int q = 0; q < 4; ++q) mx[q] = fmaxf(mx[q], sacc[j][q]);
        #pragma unroll
        for (int off = 1; off < 16; off <<= 1)
            #pragma unroll
            for (int q = 0; q < 4; ++q) mx[q] = fmaxf(mx[q], __shfl_xor(mx[q], off));

        f32x4 tau;
        #pragma unroll
        for (int q = 0; q < 4; ++q) tau[q] = mx[q] - 1.0f;

        for (int it = 0; it < 16; ++it) {
            f32x4 s, cnt;
            #pragma unroll
            for (int q = 0; q < 4; ++q) { s[q] = 0.f; cnt[q] = 0.f; }
            #pragma unroll
            for (int j = 0; j < 12; ++j)
                #pragma unroll
                for (int q = 0; q < 4; ++q)
                    if (sacc[j][q] > tau[q]) { s[q] += sacc[j][q]; cnt[q] += 1.f; }
            #pragma unroll
            for (int off = 1; off < 16; off <<= 1)
                #pragma unroll
                for (int q = 0; q < 4; ++q) {
                    s[q]   += __shfl_xor(s[q], off);
                    cnt[q] += __shfl_xor(cnt[q], off);
                }
            bool adv = false;
            #pragma unroll
            for (int q = 0; q < 4; ++q) {
                float nt = (s[q] - 1.0f) / cnt[q];
                if (nt > tau[q]) { tau[q] = nt; adv = true; }
            }
            if (!__any(adv ? 1 : 0)) break;
        }

        // scores -> Ssc (overlays dead Bz; last Bz read preceded final sync)
        #pragma unroll
        for (int q = 0; q < 4; ++q) {
            const int n = w * 16 + 4 * lg + q;
            #pragma unroll
            for (int j = 0; j < 12; ++j) {
                const int m = j * 16 + lr;
                float sv = (m < Nz) ? fmaxf(sacc[j][q] - tau[q], 0.f) : 0.f;
                Ssc[n * 200 + m] = f2bf(sv);
            }
        }
    }

    // ================= G: acc = Wg . xf (A global, B=XFfull, 0 barriers) ===
    f32x4 acc[4][4];
    #pragma unroll
    for (int i = 0; i < 4; ++i)
        #pragma unroll
        for (int j = 0; j < 4; ++j)
            #pragma unroll
            for (int e = 0; e < 4; ++e) acc[i][j][e] = 0.f;

    #pragma unroll
    for (int c = 0; c < 8; ++c) {
        const int kc = c * 32;
        bf16x8 a[4], bfr[4];
        #pragma unroll
        for (int i = 0; i < 4; ++i)
            a[i] = *(const bf16x8*)&Wg[(size_t)(w * 64 + i * 16 + lr) * C + kc + lk];
        #pragma unroll
        for (int j = 0; j < 4; ++j)
            bfr[j] = *(const bf16x8*)&XFfull[(j * 16 + lr) * 264 + kc + lk];
        #pragma unroll
        for (int i = 0; i < 4; ++i)
            #pragma unroll
            for (int j = 0; j < 4; ++j)
                acc[i][j] = __builtin_amdgcn_mfma_f32_16x16x32_bf16(a[i], bfr[j], acc[i][j], 0, 0, 0);
    }
    __syncthreads();   // XFfull reads done + Ssc writes visible

    // G epilogue: bn_relu -> XG (XOR-swizzled, overlays XFfull)
    #pragma unroll
    for (int i = 0; i < 4; ++i) {
        const int ob = w * 64 + i * 16 + lg * 4;
        float inv[4], sh[4], bi[4];
        #pragma unroll
        for (int r = 0; r < 4; ++r) {
            int o = ob + r;
            float iv = g_gamma[o] * rsqrtf(g_var[o] + EPS);
            inv[r] = iv; sh[r] = g_beta[o] - g_mean[o] * iv; bi[r] = bg[o];
        }
        #pragma unroll
        for (int j = 0; j < 4; ++j) {
            const int n = j * 16 + lr;
            unsigned short h[4];
            #pragma unroll
            for (int r = 0; r < 4; ++r)
                h[r] = f2bf(fmaxf(fmaf(acc[i][j][r] + bi[r], inv[r], sh[r]), 0.f));
            uint2 pk;
            pk.x = (unsigned)h[0] | ((unsigned)h[1] << 16);
            pk.y = (unsigned)h[2] | ((unsigned)h[3] << 16);
            *(uint2*)&XG[XGIDX(n, ob)] = pk;
        }
    }
    #pragma unroll
    for (int i = 0; i < 4; ++i)
        #pragma unroll
        for (int j = 0; j < 4; ++j)
            #pragma unroll
            for (int e = 0; e < 4; ++e) acc[i][j][e] = 0.f;
    __syncthreads();   // XG visible — last barrier of the kernel

    // ================= P1: acc += zg2 . Ssc =================
    #pragma unroll
    for (int c = 0; c < 6; ++c) {
        const int kc = c * 32;
        bf16x8 a[4], bfr[4];
        #pragma unroll
        for (int i = 0; i < 4; ++i)
            a[i] = *(const bf16x8*)&Zg2b[(size_t)(w * 64 + i * 16 + lr) * NzP + kc + lk];
        #pragma unroll
        for (int j = 0; j < 4; ++j)
            bfr[j] = *(const bf16x8*)&Ssc[(j * 16 + lr) * 200 + kc + lk];
        #pragma unroll
        for (int i = 0; i < 4; ++i)
            #pragma unroll
            for (int j = 0; j < 4; ++j)
                acc[i][j] = __builtin_amdgcn_mfma_f32_16x16x32_bf16(a[i], bfr[j], acc[i][j], 0, 0, 0);
    }

    // ================= P2: acc += Wf2 . XG =================
    #pragma unroll
    for (int c = 0; c < 8; ++c) {
        const int kc = c * 32;
        bf16x8 a[4], bfr[4];
        #pragma unroll
        for (int i = 0; i < 4; ++i)
            a[i] = *(const bf16x8*)&Wf2[(size_t)(w * 64 + i * 16 + lr) * 512 + kc + lk];
        #pragma unroll
        for (int j = 0; j < 4; ++j)
            bfr[j] = *(const bf16x8*)&XG[XGIDX(j * 16 + lr, kc + lk)];
        #pragma unroll
        for (int i = 0; i < 4; ++i)
            #pragma unroll
            for (int j = 0; j < 4; ++j)
                acc[i][j] = __builtin_amdgcn_mfma_f32_16x16x32_bf16(a[i], bfr[j], acc[i][j], 0, 0, 0);
    }

    // final epilogue: bn_relu(f) -> out f32 [b][256][Nx]
    #pragma unroll
    for (int i = 0; i < 4; ++i) {
        const int ob = w * 64 + i * 16 + lg * 4;
        float inv[4], sh[4], bi[4];
        #pragma unroll
        for (int r = 0; r < 4; ++r) {
            int o = ob + r;
            float iv = f_gamma[o] * rsqrtf(f_var[o] + EPS);
            inv[r] = iv; sh[r] = f_beta[o] - f_mean[o] * iv; bi[r] = bf[o];
        }
        #pragma unroll
        for (int j = 0; j < 4; ++j) {
            const int gn = n0 + j * 16 + lr;
            if (gn < Nx) {
                #pragma unroll
                for (int r = 0; r < 4; ++r) {
                    float v = fmaxf(fmaf(acc[i][j][r] + bi[r], inv[r], sh[r]), 0.f);
                    out[((size_t)b * C + ob + r) * Nx + gn] = v;
                }
            }
        }
    }
}

// ---------------------------------------------------------------------------
extern "C" void kernel_launch(void* const* d_in, const int* in_sizes, int n_in,
                              void* d_out, int out_size, void* d_ws, size_t ws_size,
                              hipStream_t stream)
{
    const float* zf      = (const float*)d_in[0];
    const float* xf      = (const float*)d_in[1];
    const float* Wq      = (const float*)d_in[2];
    const float* bq      = (const float*)d_in[3];
    const float* Ws_     = (const float*)d_in[4];
    const float* bs      = (const float*)d_in[5];
    const float* Wg      = (const float*)d_in[6];
    const float* bg      = (const float*)d_in[7];
    const float* g_gamma = (const float*)d_in[8];
    const float* g_beta  = (const float*)d_in[9];
    const float* g_mean  = (const float*)d_in[10];
    const float* g_var   = (const float*)d_in[11];
    const float* Wf      = (const float*)d_in[12];
    const float* bf_     = (const float*)d_in[13];
    const float* f_gamma = (const float*)d_in[14];
    const float* f_beta  = (const float*)d_in[15];
    const float* f_mean  = (const float*)d_in[16];
    const float* f_var   = (const float*)d_in[17];
    float* out = (float*)d_out;

    typedef unsigned short u16;
    char* ws = (char*)d_ws;
    u16*   zfT_hi = (u16*)(ws);                   //  11,075,584
    u16*   zfT_lo = (u16*)(ws +  11075584);       //  11,075,584
    u16*   zqT_hi = (u16*)(ws +  22151168);       //  12,582,912
    u16*   zqT_lo = (u16*)(ws +  34734080);       //  12,582,912
    u16*   zf_gT  = (u16*)(ws +  47316992);       //  12,582,912
    u16*   zg2    = (u16*)(ws +  59899904);       //  12,582,912
    float* U      = (float*)(ws +  72482816);     //      98,304
    u16*   Mhi    = (u16*)(ws +  72581120);       //     131,072
    u16*   Mlo    = (u16*)(ws +  72712192);       //     131,072
    u16*   Wg_bf  = (u16*)(ws +  72843264);       //     131,072
    u16*   Wf_bf  = (u16*)(ws +  72974336);       //     262,144
    float* wv     = (float*)(ws +  73236480);     //       1,024
    float* wu     = (float*)(ws +  73237504);     //       1,024
    float* c0     = (float*)(ws +  73238528);     //         256

    dim3 blk(256);
    const int gx_x = (Nx + 63) / 64;   // 10
    const int gx_z = NzP / 64;         // 3

    prep_all<<<dim3(2193), blk, 0, stream>>>(
        zf, Wq, bq, Ws_, bs, Wg, Wf,
        Wg_bf, Wf_bf, wv, wu, c0, Mhi, Mlo, U, zfT_hi, zfT_lo);

    z_gemm<<<dim3(gx_z, C / 64, Bb), blk, 0, stream>>>(
        Mhi, Mlo, Wg_bf, zfT_hi, zfT_lo, wv,
        bg, g_gamma, g_beta, g_mean, g_var,
        zqT_hi, zqT_lo, zf_gT);

    zg2_gemm<<<dim3(gx_z, C / 64, Bb), blk, 0, stream>>>(
        Wf_bf, 2 * C, zf_gT, zg2, NzP, NzP, C, C);

    mega_x<<<dim3(gx_x, 1, Bb), blk, 0, stream>>>(
        xf, zqT_hi, zqT_lo, Wg_bf, zg2, Wf_bf + C, U,
        bg, g_gamma, g_beta, g_mean, g_var,
        bf_, f_gamma, f_beta, f_mean, f_var, out);
}

// Round 17
// 189.195 us; speedup vs baseline: 1.1929x; 1.0519x over previous
//
#include <hip/hip_runtime.h>
#include <math.h>

#define EPS 1e-5f

constexpr int Bb  = 128;
constexpr int C   = 256;
constexpr int Nz  = 169;   // 13*13
constexpr int Nx  = 625;   // 25*25
constexpr int NzP = 192;   // Nz padded (zero-filled)

typedef __bf16 bf16x8 __attribute__((ext_vector_type(8)));
typedef float  f32x4  __attribute__((ext_vector_type(4)));

__device__ __forceinline__ unsigned short f2bf(float f) {
    union { float f; unsigned u; } x; x.f = f;
    unsigned r = x.u + 0x7FFFu + ((x.u >> 16) & 1u);   // RNE
    return (unsigned short)(r >> 16);
}
__device__ __forceinline__ float bf2f(unsigned short h) {
    union { unsigned u; float f; } x; x.u = ((unsigned)h) << 16;
    return x.f;
}

// ---------------------------------------------------------------------------
// prep_all (529 blocks):
//   [0,512)   : Wg,Wf -> bf16
//   512       : wv = Wq^T bs, wu = Ws^T bq, c0 = bq.bs
//   [513,529) : M = Wq^T Ws (fp32, split bf16 out)
// (zf transpose & bias_u removed — handled by z_full; fixes the intra-launch
//  wu race that bias_u had.)
// ---------------------------------------------------------------------------
__global__ __launch_bounds__(256)
void prep_all(const float* __restrict__ Wq, const float* __restrict__ bq,
              const float* __restrict__ Ws, const float* __restrict__ bs,
              const float* __restrict__ Wg, const float* __restrict__ Wf,
              unsigned short* __restrict__ Wg_bf, unsigned short* __restrict__ Wf_bf,
              float* __restrict__ wv, float* __restrict__ wu, float* __restrict__ c0,
              unsigned short* __restrict__ Mhi, unsigned short* __restrict__ Mlo)
{
    __shared__ float T[32][65];
    const int bx = blockIdx.x, tid = threadIdx.x;

    if (bx < 512) {
        int i = bx * 256 + tid;
        if (i < C * C) Wg_bf[i] = f2bf(Wg[i]);
        if (i < C * 2 * C) Wf_bf[i] = f2bf(Wf[i]);
        return;
    }
    if (bx == 512) {
        float a = 0.f, b = 0.f;
        for (int o = 0; o < C; ++o) {
            a += Wq[o * C + tid] * bs[o];
            b += Ws[o * C + tid] * bq[o];
        }
        wv[tid] = a;
        wu[tid] = b;
        if (tid == 0) {
            float c = 0.f;
            for (int o = 0; o < C; ++o) c += bq[o] * bs[o];
            c0[0] = c;
        }
        return;
    }
    {
        const int t  = bx - 513;
        const int j0 = (t & 3) * 64, i0 = (t >> 2) * 64;
        const int tx = tid & 15, ty = tid >> 4;
        float (*Qs)[65] = (float(*)[65])&T[0][0];
        float (*Ss)[65] = (float(*)[65])&T[16][0];
        float acc[4][4] = {};

        for (int kc = 0; kc < C; kc += 16) {
            #pragma unroll
            for (int i = 0; i < 4; ++i) {
                int e = tid + 256 * i;
                int k = e >> 6, col = e & 63;
                Qs[k][col] = Wq[(size_t)(kc + k) * C + i0 + col];
                Ss[k][col] = Ws[(size_t)(kc + k) * C + j0 + col];
            }
            __syncthreads();
            #pragma unroll
            for (int k = 0; k < 16; ++k) {
                float a[4], bv[4];
                #pragma unroll
                for (int i = 0; i < 4; ++i) a[i] = Qs[k][ty * 4 + i];
                #pragma unroll
                for (int j = 0; j < 4; ++j) bv[j] = Ss[k][tx * 4 + j];
                #pragma unroll
                for (int i = 0; i < 4; ++i)
                    #pragma unroll
                    for (int j = 0; j < 4; ++j)
                        acc[i][j] = fmaf(a[i], bv[j], acc[i][j]);
            }
            __syncthreads();
        }
        #pragma unroll
        for (int i = 0; i < 4; ++i)
            #pragma unroll
            for (int j = 0; j < 4; ++j) {
                float v = acc[i][j];
                unsigned short h = f2bf(v);
                size_t idx = (size_t)(i0 + ty * 4 + i) * C + j0 + tx * 4 + j;
                Mhi[idx] = h;
                Mlo[idx] = f2bf(v - bf2f(h));
            }
    }
}

// ---------------------------------------------------------------------------
// z_full: per (b, 64-m tile) — full-O z-side megakernel.
//  stage: zf f32 -> hi/lo bf16 LDS tiles Zh/Zl [64][264] (read ONCE)
//  U    : U[b,m] = wu . zf[:,m] + c0 (from the staged tile)
//  zq'  : M.zf + wv (split x3 MFMA, A direct from L2) -> split bf16 out
//  zf_g : bn_relu(Wg.zf) kept in LDS (overlays dead Zl) — no global trip
//  zg2  : Wf1.zf_g (B from LDS) -> [b][256][192]
// 3 barriers total. LDS 67.6K + UP -> 2 blocks/CU.
// ---------------------------------------------------------------------------
__global__ __launch_bounds__(256)
void z_full(const float* __restrict__ zf,
            const unsigned short* __restrict__ Mhi,
            const unsigned short* __restrict__ Mlo,
            const unsigned short* __restrict__ Wg,
            const unsigned short* __restrict__ Wf1,   // Wf_bf, lda 512
            const float* __restrict__ wv, const float* __restrict__ wu,
            const float* __restrict__ c0,
            const float* __restrict__ bg, const float* __restrict__ g_gamma,
            const float* __restrict__ g_beta, const float* __restrict__ g_mean,
            const float* __restrict__ g_var,
            unsigned short* __restrict__ Yqh, unsigned short* __restrict__ Yql,
            unsigned short* __restrict__ Zg2out, float* __restrict__ U)
{
    __shared__ __attribute__((aligned(16))) char pool[67584];
    __shared__ float UP[64][5];

    unsigned short* Zh = (unsigned short*)(pool);            // [64][264]
    unsigned short* Zl = (unsigned short*)(pool + 33792);    // [64][264]
    unsigned short* ZG = (unsigned short*)(pool + 33792);    // [64][264] (post-zq')

    const int b  = blockIdx.z;
    const int n0 = blockIdx.x * 64;

    const int tid = threadIdx.x;
    const int lane = tid & 63, w = tid >> 6;
    const int lr = lane & 15, lg = lane >> 4, lk = lg * 8;
    const int brow = tid >> 2, bseg = tid & 3;

    const int gnA = min(n0 + brow, Nz - 1);

    // ---- stage zf (all 8 chunks, one barrier) ----
    #pragma unroll
    for (int c = 0; c < 8; ++c) {
        const int kc = c * 32;
        const float* src = zf + ((size_t)b * C + kc + bseg * 8) * Nz + gnA;
        unsigned short h[8], l[8];
        #pragma unroll
        for (int e = 0; e < 8; ++e) {
            float v = src[(size_t)e * Nz];
            h[e] = f2bf(v);
            l[e] = f2bf(v - bf2f(h[e]));
        }
        uint4 ph, pl;
        ph.x = (unsigned)h[0] | ((unsigned)h[1] << 16);
        ph.y = (unsigned)h[2] | ((unsigned)h[3] << 16);
        ph.z = (unsigned)h[4] | ((unsigned)h[5] << 16);
        ph.w = (unsigned)h[6] | ((unsigned)h[7] << 16);
        pl.x = (unsigned)l[0] | ((unsigned)l[1] << 16);
        pl.y = (unsigned)l[2] | ((unsigned)l[3] << 16);
        pl.z = (unsigned)l[4] | ((unsigned)l[5] << 16);
        pl.w = (unsigned)l[6] | ((unsigned)l[7] << 16);
        *(uint4*)&Zh[brow * 264 + kc + bseg * 8] = ph;
        *(uint4*)&Zl[brow * 264 + kc + bseg * 8] = pl;
    }
    __syncthreads();

    // ---- U[b, n0+r] = wu . zf[:,r] + c0 ----
    {
        const int r = tid & 63, q = tid >> 6;
        float s = 0.f;
        for (int k = q * 64; k < q * 64 + 64; ++k)
            s += wu[k] * (bf2f(Zh[r * 264 + k]) + bf2f(Zl[r * 264 + k]));
        UP[r][q] = s;
    }
    __syncthreads();
    if (tid < 64) {
        const int gn = n0 + tid;
        float val = 0.f;
        if (gn < Nz)
            val = UP[tid][0] + UP[tid][1] + UP[tid][2] + UP[tid][3] + c0[0];
        U[(size_t)b * NzP + gn] = val;
    }

    // ---- zq' = M.zf + wv (split x3, A direct) ----
    {
        f32x4 accq[4][4];
        #pragma unroll
        for (int i = 0; i < 4; ++i)
            #pragma unroll
            for (int j = 0; j < 4; ++j)
                #pragma unroll
                for (int e = 0; e < 4; ++e) accq[i][j][e] = 0.f;

        #pragma unroll
        for (int c = 0; c < 8; ++c) {
            const int kc = c * 32;
            bf16x8 ah[4], al[4], bh[4], bl[4];
            #pragma unroll
            for (int i = 0; i < 4; ++i) {
                ah[i] = *(const bf16x8*)&Mhi[(size_t)(w * 64 + i * 16 + lr) * C + kc + lk];
                al[i] = *(const bf16x8*)&Mlo[(size_t)(w * 64 + i * 16 + lr) * C + kc + lk];
            }
            #pragma unroll
            for (int j = 0; j < 4; ++j) {
                bh[j] = *(const bf16x8*)&Zh[(j * 16 + lr) * 264 + kc + lk];
                bl[j] = *(const bf16x8*)&Zl[(j * 16 + lr) * 264 + kc + lk];
            }
            #pragma unroll
            for (int i = 0; i < 4; ++i)
                #pragma unroll
                for (int j = 0; j < 4; ++j) {
                    accq[i][j] = __builtin_amdgcn_mfma_f32_16x16x32_bf16(al[i], bh[j], accq[i][j], 0, 0, 0);
                    accq[i][j] = __builtin_amdgcn_mfma_f32_16x16x32_bf16(ah[i], bl[j], accq[i][j], 0, 0, 0);
                    accq[i][j] = __builtin_amdgcn_mfma_f32_16x16x32_bf16(ah[i], bh[j], accq[i][j], 0, 0, 0);
                }
        }

        // epilogue: split bf16 write [b][192][256], rows >= Nz zeroed
        #pragma unroll
        for (int i = 0; i < 4; ++i) {
            const int ob = w * 64 + i * 16 + lg * 4;
            float bi[4];
            #pragma unroll
            for (int r = 0; r < 4; ++r) bi[r] = wv[ob + r];
            #pragma unroll
            for (int j = 0; j < 4; ++j) {
                const int gn = n0 + j * 16 + lr;
                uint2 ph = make_uint2(0, 0), pl = make_uint2(0, 0);
                if (gn < Nz) {
                    unsigned short h[4], l[4];
                    #pragma unroll
                    for (int r = 0; r < 4; ++r) {
                        float v = accq[i][j][r] + bi[r];
                        h[r] = f2bf(v);
                        l[r] = f2bf(v - bf2f(h[r]));
                    }
                    ph.x = (unsigned)h[0] | ((unsigned)h[1] << 16);
                    ph.y = (unsigned)h[2] | ((unsigned)h[3] << 16);
                    pl.x = (unsigned)l[0] | ((unsigned)l[1] << 16);
                    pl.y = (unsigned)l[2] | ((unsigned)l[3] << 16);
                }
                size_t idx = ((size_t)b * NzP + gn) * C + ob;
                *(uint2*)&Yqh[idx] = ph;
                *(uint2*)&Yql[idx] = pl;
            }
        }
    }

    // ---- zf_g = bn_relu(Wg.zf) -> ZG LDS (overlays Zl) ----
    f32x4 acc[4][4];
    #pragma unroll
    for (int i = 0; i < 4; ++i)
        #pragma unroll
        for (int j = 0; j < 4; ++j)
            #pragma unroll
            for (int e = 0; e < 4; ++e) acc[i][j][e] = 0.f;

    #pragma unroll
    for (int c = 0; c < 8; ++c) {
        const int kc = c * 32;
        bf16x8 a[4], bfr[4];
        #pragma unroll
        for (int i = 0; i < 4; ++i)
            a[i] = *(const bf16x8*)&Wg[(size_t)(w * 64 + i * 16 + lr) * C + kc + lk];
        #pragma unroll
        for (int j = 0; j < 4; ++j)
            bfr[j] = *(const bf16x8*)&Zh[(j * 16 + lr) * 264 + kc + lk];
        #pragma unroll
        for (int i = 0; i < 4; ++i)
            #pragma unroll
            for (int j = 0; j < 4; ++j)
                acc[i][j] = __builtin_amdgcn_mfma_f32_16x16x32_bf16(a[i], bfr[j], acc[i][j], 0, 0, 0);
    }
    __syncthreads();   // all Zl reads (zq') complete before ZG overlays it

    #pragma unroll
    for (int i = 0; i < 4; ++i) {
        const int ob = w * 64 + i * 16 + lg * 4;
        float inv[4], sh[4], bi[4];
        #pragma unroll
        for (int r = 0; r < 4; ++r) {
            int o = ob + r;
            float iv = g_gamma[o] * rsqrtf(g_var[o] + EPS);
            inv[r] = iv; sh[r] = g_beta[o] - g_mean[o] * iv; bi[r] = bg[o];
        }
        #pragma unroll
        for (int j = 0; j < 4; ++j) {
            const int n = j * 16 + lr;
            unsigned short h[4];
            #pragma unroll
            for (int r = 0; r < 4; ++r)
                h[r] = f2bf(fmaxf(fmaf(acc[i][j][r] + bi[r], inv[r], sh[r]), 0.f));
            uint2 pk;
            pk.x = (unsigned)h[0] | ((unsigned)h[1] << 16);
            pk.y = (unsigned)h[2] | ((unsigned)h[3] << 16);
            *(uint2*)&ZG[n * 264 + ob] = pk;
        }
    }
    #pragma unroll
    for (int i = 0; i < 4; ++i)
        #pragma unroll
        for (int j = 0; j < 4; ++j)
            #pragma unroll
            for (int e = 0; e < 4; ++e) acc[i][j][e] = 0.f;
    __syncthreads();   // ZG visible

    // ---- zg2 = Wf1.zf_g (A direct, B=ZG LDS) ----
    #pragma unroll
    for (int c = 0; c < 8; ++c) {
        const int kc = c * 32;
        bf16x8 a[4], bfr[4];
        #pragma unroll
        for (int i = 0; i < 4; ++i)
            a[i] = *(const bf16x8*)&Wf1[(size_t)(w * 64 + i * 16 + lr) * 512 + kc + lk];
        #pragma unroll
        for (int j = 0; j < 4; ++j)
            bfr[j] = *(const bf16x8*)&ZG[(j * 16 + lr) * 264 + kc + lk];
        #pragma unroll
        for (int i = 0; i < 4; ++i)
            #pragma unroll
            for (int j = 0; j < 4; ++j)
                acc[i][j] = __builtin_amdgcn_mfma_f32_16x16x32_bf16(a[i], bfr[j], acc[i][j], 0, 0, 0);
    }

    // zg2 write: [b][256][192]
    #pragma unroll
    for (int i = 0; i < 4; ++i) {
        const int ob = w * 64 + i * 16 + lg * 4;
        #pragma unroll
        for (int j = 0; j < 4; ++j) {
            const int gm = n0 + j * 16 + lr;
            #pragma unroll
            for (int r = 0; r < 4; ++r)
                Zg2out[((size_t)b * C + ob + r) * NzP + gm] = f2bf(acc[i][j][r]);
        }
    }
}

// ---------------------------------------------------------------------------
// X-side megakernel (unchanged from round 16).
// ---------------------------------------------------------------------------
#define XGIDX(n, o) ((((n) << 8) + (o)) ^ (((n) & 7) << 3))

__global__ __launch_bounds__(256)
void mega_x(const float* __restrict__ Xf,
            const unsigned short* __restrict__ Zqh,   // [b][192][256]
            const unsigned short* __restrict__ Zql,
            const unsigned short* __restrict__ Wg,    // [256][256]
            const unsigned short* __restrict__ Zg2,   // [b][256][192]
            const unsigned short* __restrict__ Wf2,   // [256][512] base+256
            const float* __restrict__ U,              // [b][192]
            const float* __restrict__ bg, const float* __restrict__ g_gamma,
            const float* __restrict__ g_beta, const float* __restrict__ g_mean,
            const float* __restrict__ g_var,
            const float* __restrict__ bf, const float* __restrict__ f_gamma,
            const float* __restrict__ f_beta, const float* __restrict__ f_mean,
            const float* __restrict__ f_var,
            float* __restrict__ out)
{
    __shared__ __attribute__((aligned(16))) char pool[69632];
    __shared__ float Us[192];

    unsigned short* XFfull = (unsigned short*)(pool);          // [64][264] hi (sim A + G B)
    unsigned short* XG     = (unsigned short*)(pool);          // [64][256] swz (post-G)
    unsigned short* Bzh    = (unsigned short*)(pool + 33792);  // [192][40]
    unsigned short* Bzl    = (unsigned short*)(pool + 49152);  // [192][40]
    unsigned short* Ssc    = (unsigned short*)(pool + 33792);  // [64][200] (post-sim)
    unsigned short* XFl    = (unsigned short*)(pool + 64512);  // [64][40] lo scratch

    const int g0  = blockIdx.z * gridDim.x + blockIdx.x;
    const int rid = (g0 & 7) * 160 + (g0 >> 3);
    const int b   = rid / 10;
    const int n0  = (rid % 10) * 64;

    const int tid = threadIdx.x;
    const int lane = tid & 63, w = tid >> 6;
    const int lr = lane & 15, lg = lane >> 4, lk = lg * 8;
    const int brow = tid >> 2, bseg = tid & 3;

    const unsigned short* Zqhb = Zqh + (size_t)b * NzP * C;
    const unsigned short* Zqlb = Zql + (size_t)b * NzP * C;
    const unsigned short* Zg2b = Zg2 + (size_t)b * C * NzP;

    if (tid < 192) Us[tid] = U[(size_t)b * NzP + tid];

    const int gnA = min(n0 + brow, Nx - 1);

    // ================= sim phase =================
    {
        f32x4 sacc[12];
        #pragma unroll
        for (int j = 0; j < 12; ++j)
            #pragma unroll
            for (int e = 0; e < 4; ++e) sacc[j][e] = 0.f;

        for (int kc = 0; kc < C; kc += 32) {
            {
                const float* src = Xf + ((size_t)b * C + kc + bseg * 8) * Nx + gnA;
                unsigned short h[8], l[8];
                #pragma unroll
                for (int e = 0; e < 8; ++e) {
                    float v = src[(size_t)e * Nx];
                    h[e] = f2bf(v);
                    l[e] = f2bf(v - bf2f(h[e]));
                }
                uint4 ph, pl;
                ph.x = (unsigned)h[0] | ((unsigned)h[1] << 16);
                ph.y = (unsigned)h[2] | ((unsigned)h[3] << 16);
                ph.z = (unsigned)h[4] | ((unsigned)h[5] << 16);
                ph.w = (unsigned)h[6] | ((unsigned)h[7] << 16);
                pl.x = (unsigned)l[0] | ((unsigned)l[1] << 16);
                pl.y = (unsigned)l[2] | ((unsigned)l[3] << 16);
                pl.z = (unsigned)l[4] | ((unsigned)l[5] << 16);
                pl.w = (unsigned)l[6] | ((unsigned)l[7] << 16);
                *(uint4*)&XFfull[brow * 264 + kc + bseg * 8] = ph;
                *(uint4*)&XFl[brow * 40 + bseg * 8] = pl;
            }
            #pragma unroll
            for (int i = 0; i < 3; ++i) {
                const int slot = tid + 256 * i;
                const int r = slot >> 2, s = slot & 3;
                const int gk = kc + s * 8;
                *(int4*)&Bzh[r * 40 + s * 8] = *(const int4*)&Zqhb[(size_t)r * C + gk];
                *(int4*)&Bzl[r * 40 + s * 8] = *(const int4*)&Zqlb[(size_t)r * C + gk];
            }
            __syncthreads();

            bf16x8 a0h = *(const bf16x8*)&XFfull[(w * 16 + lr) * 264 + kc + lk];
            bf16x8 a0l = *(const bf16x8*)&XFl[(w * 16 + lr) * 40 + lk];
            #pragma unroll
            for (int j = 0; j < 12; ++j) {
                bf16x8 bh = *(const bf16x8*)&Bzh[(j * 16 + lr) * 40 + lk];
                bf16x8 bl = *(const bf16x8*)&Bzl[(j * 16 + lr) * 40 + lk];
                sacc[j] = __builtin_amdgcn_mfma_f32_16x16x32_bf16(a0l, bh, sacc[j], 0, 0, 0);
                sacc[j] = __builtin_amdgcn_mfma_f32_16x16x32_bf16(a0h, bl, sacc[j], 0, 0, 0);
                sacc[j] = __builtin_amdgcn_mfma_f32_16x16x32_bf16(a0h, bh, sacc[j], 0, 0, 0);
            }
            __syncthreads();
        }

        #pragma unroll
        for (int j = 0; j < 12; ++j) {
            const int m = j * 16 + lr;
            const float uv = Us[m];
            const bool bad = (m >= Nz);
            #pragma unroll
            for (int q = 0; q < 4; ++q)
                sacc[j][q] = bad ? -1e30f : (sacc[j][q] + uv);
        }

        f32x4 mx = sacc[0];
        #pragma unroll
        for (int j = 1; j < 12; ++j)
            #pragma unroll
            for (int q = 0; q < 4; ++q) mx[q] = fmaxf(mx[q], sacc[j][q]);
        #pragma unroll
        for (int off = 1; off < 16; off <<= 1)
            #pragma unroll
            for (int q = 0; q < 4; ++q) mx[q] = fmaxf(mx[q], __shfl_xor(mx[q], off));

        f32x4 tau;
        #pragma unroll
        for (int q = 0; q < 4; ++q) tau[q] = mx[q] - 1.0f;

        for (int it = 0; it < 16; ++it) {
            f32x4 s, cnt;
            #pragma unroll
            for (int q = 0; q < 4; ++q) { s[q] = 0.f; cnt[q] = 0.f; }
            #pragma unroll
            for (int j = 0; j < 12; ++j)
                #pragma unroll
                for (int q = 0; q < 4; ++q)
                    if (sacc[j][q] > tau[q]) { s[q] += sacc[j][q]; cnt[q] += 1.f; }
            #pragma unroll
            for (int off = 1; off < 16; off <<= 1)
                #pragma unroll
                for (int q = 0; q < 4; ++q) {
                    s[q]   += __shfl_xor(s[q], off);
                    cnt[q] += __shfl_xor(cnt[q], off);
                }
            bool adv = false;
            #pragma unroll
            for (int q = 0; q < 4; ++q) {
                float nt = (s[q] - 1.0f) / cnt[q];
                if (nt > tau[q]) { tau[q] = nt; adv = true; }
            }
            if (!__any(adv ? 1 : 0)) break;
        }

        #pragma unroll
        for (int q = 0; q < 4; ++q) {
            const int n = w * 16 + 4 * lg + q;
            #pragma unroll
            for (int j = 0; j < 12; ++j) {
                const int m = j * 16 + lr;
                float sv = (m < Nz) ? fmaxf(sacc[j][q] - tau[q], 0.f) : 0.f;
                Ssc[n * 200 + m] = f2bf(sv);
            }
        }
    }

    // ================= G: acc = Wg . xf (A global, B=XFfull, 0 barriers) ===
    f32x4 acc[4][4];
    #pragma unroll
    for (int i = 0; i < 4; ++i)
        #pragma unroll
        for (int j = 0; j < 4; ++j)
            #pragma unroll
            for (int e = 0; e < 4; ++e) acc[i][j][e] = 0.f;

    #pragma unroll
    for (int c = 0; c < 8; ++c) {
        const int kc = c * 32;
        bf16x8 a[4], bfr[4];
        #pragma unroll
        for (int i = 0; i < 4; ++i)
            a[i] = *(const bf16x8*)&Wg[(size_t)(w * 64 + i * 16 + lr) * C + kc + lk];
        #pragma unroll
        for (int j = 0; j < 4; ++j)
            bfr[j] = *(const bf16x8*)&XFfull[(j * 16 + lr) * 264 + kc + lk];
        #pragma unroll
        for (int i = 0; i < 4; ++i)
            #pragma unroll
            for (int j = 0; j < 4; ++j)
                acc[i][j] = __builtin_amdgcn_mfma_f32_16x16x32_bf16(a[i], bfr[j], acc[i][j], 0, 0, 0);
    }
    __syncthreads();

    #pragma unroll
    for (int i = 0; i < 4; ++i) {
        const int ob = w * 64 + i * 16 + lg * 4;
        float inv[4], sh[4], bi[4];
        #pragma unroll
        for (int r = 0; r < 4; ++r) {
            int o = ob + r;
            float iv = g_gamma[o] * rsqrtf(g_var[o] + EPS);
            inv[r] = iv; sh[r] = g_beta[o] - g_mean[o] * iv; bi[r] = bg[o];
        }
        #pragma unroll
        for (int j = 0; j < 4; ++j) {
            const int n = j * 16 + lr;
            unsigned short h[4];
            #pragma unroll
            for (int r = 0; r < 4; ++r)
                h[r] = f2bf(fmaxf(fmaf(acc[i][j][r] + bi[r], inv[r], sh[r]), 0.f));
            uint2 pk;
            pk.x = (unsigned)h[0] | ((unsigned)h[1] << 16);
            pk.y = (unsigned)h[2] | ((unsigned)h[3] << 16);
            *(uint2*)&XG[XGIDX(n, ob)] = pk;
        }
    }
    #pragma unroll
    for (int i = 0; i < 4; ++i)
        #pragma unroll
        for (int j = 0; j < 4; ++j)
            #pragma unroll
            for (int e = 0; e < 4; ++e) acc[i][j][e] = 0.f;
    __syncthreads();

    // ================= P1: acc += zg2 . Ssc =================
    #pragma unroll
    for (int c = 0; c < 6; ++c) {
        const int kc = c * 32;
        bf16x8 a[4], bfr[4];
        #pragma unroll
        for (int i = 0; i < 4; ++i)
            a[i] = *(const bf16x8*)&Zg2b[(size_t)(w * 64 + i * 16 + lr) * NzP + kc + lk];
        #pragma unroll
        for (int j = 0; j < 4; ++j)
            bfr[j] = *(const bf16x8*)&Ssc[(j * 16 + lr) * 200 + kc + lk];
        #pragma unroll
        for (int i = 0; i < 4; ++i)
            #pragma unroll
            for (int j = 0; j < 4; ++j)
                acc[i][j] = __builtin_amdgcn_mfma_f32_16x16x32_bf16(a[i], bfr[j], acc[i][j], 0, 0, 0);
    }

    // ================= P2: acc += Wf2 . XG =================
    #pragma unroll
    for (int c = 0; c < 8; ++c) {
        const int kc = c * 32;
        bf16x8 a[4], bfr[4];
        #pragma unroll
        for (int i = 0; i < 4; ++i)
            a[i] = *(const bf16x8*)&Wf2[(size_t)(w * 64 + i * 16 + lr) * 512 + kc + lk];
        #pragma unroll
        for (int j = 0; j < 4; ++j)
            bfr[j] = *(const bf16x8*)&XG[XGIDX(j * 16 + lr, kc + lk)];
        #pragma unroll
        for (int i = 0; i < 4; ++i)
            #pragma unroll
            for (int j = 0; j < 4; ++j)
                acc[i][j] = __builtin_amdgcn_mfma_f32_16x16x32_bf16(a[i], bfr[j], acc[i][j], 0, 0, 0);
    }

    // final epilogue: bn_relu(f) -> out f32 [b][256][Nx]
    #pragma unroll
    for (int i = 0; i < 4; ++i) {
        const int ob = w * 64 + i * 16 + lg * 4;
        float inv[4], sh[4], bi[4];
        #pragma unroll
        for (int r = 0; r < 4; ++r) {
            int o = ob + r;
            float iv = f_gamma[o] * rsqrtf(f_var[o] + EPS);
            inv[r] = iv; sh[r] = f_beta[o] - f_mean[o] * iv; bi[r] = bf[o];
        }
        #pragma unroll
        for (int j = 0; j < 4; ++j) {
            const int gn = n0 + j * 16 + lr;
            if (gn < Nx) {
                #pragma unroll
                for (int r = 0; r < 4; ++r) {
                    float v = fmaxf(fmaf(acc[i][j][r] + bi[r], inv[r], sh[r]), 0.f);
                    out[((size_t)b * C + ob + r) * Nx + gn] = v;
                }
            }
        }
    }
}

// ---------------------------------------------------------------------------
extern "C" void kernel_launch(void* const* d_in, const int* in_sizes, int n_in,
                              void* d_out, int out_size, void* d_ws, size_t ws_size,
                              hipStream_t stream)
{
    const float* zf      = (const float*)d_in[0];
    const float* xf      = (const float*)d_in[1];
    const float* Wq      = (const float*)d_in[2];
    const float* bq      = (const float*)d_in[3];
    const float* Ws_     = (const float*)d_in[4];
    const float* bs      = (const float*)d_in[5];
    const float* Wg      = (const float*)d_in[6];
    const float* bg      = (const float*)d_in[7];
    const float* g_gamma = (const float*)d_in[8];
    const float* g_beta  = (const float*)d_in[9];
    const float* g_mean  = (const float*)d_in[10];
    const float* g_var   = (const float*)d_in[11];
    const float* Wf      = (const float*)d_in[12];
    const float* bf_     = (const float*)d_in[13];
    const float* f_gamma = (const float*)d_in[14];
    const float* f_beta  = (const float*)d_in[15];
    const float* f_mean  = (const float*)d_in[16];
    const float* f_var   = (const float*)d_in[17];
    float* out = (float*)d_out;

    typedef unsigned short u16;
    char* ws = (char*)d_ws;
    u16*   zqT_hi = (u16*)(ws);                   //  12,582,912
    u16*   zqT_lo = (u16*)(ws +  12582912);       //  12,582,912
    u16*   zg2    = (u16*)(ws +  25165824);       //  12,582,912
    float* U      = (float*)(ws +  37748736);     //      98,304
    u16*   Mhi    = (u16*)(ws +  37847040);       //     131,072
    u16*   Mlo    = (u16*)(ws +  37978112);       //     131,072
    u16*   Wg_bf  = (u16*)(ws +  38109184);       //     131,072
    u16*   Wf_bf  = (u16*)(ws +  38240256);       //     262,144
    float* wv     = (float*)(ws +  38502400);     //       1,024
    float* wu     = (float*)(ws +  38503424);     //       1,024
    float* c0     = (float*)(ws +  38504448);     //         256

    dim3 blk(256);
    const int gx_x = (Nx + 63) / 64;   // 10
    const int gx_z = NzP / 64;         // 3

    // 1) weight conversions + wv/wu/c0 + M = Wq^T Ws
    prep_all<<<dim3(529), blk, 0, stream>>>(
        Wq, bq, Ws_, bs, Wg, Wf,
        Wg_bf, Wf_bf, wv, wu, c0, Mhi, Mlo);

    // 2) z-side megakernel: zf staged once -> U, zq' (split), zf_g (LDS), zg2
    z_full<<<dim3(gx_z, 1, Bb), blk, 0, stream>>>(
        zf, Mhi, Mlo, Wg_bf, Wf_bf, wv, wu, c0,
        bg, g_gamma, g_beta, g_mean, g_var,
        zqT_hi, zqT_lo, zg2, U);

    // 3) x-side megakernel
    mega_x<<<dim3(gx_x, 1, Bb), blk, 0, stream>>>(
        xf, zqT_hi, zqT_lo, Wg_bf, zg2, Wf_bf + C, U,
        bg, g_gamma, g_beta, g_mean, g_var,
        bf_, f_gamma, f_beta, f_mean, f_var, out);
}